// Round 9
// baseline (181.043 us; speedup 1.0000x reference)
//
#include <hip/hip_runtime.h>
#include <math.h>

#define KDIM 128
#define TLEN 512
#define BATCH 16
#define CH_L 16
#define NCH 32           // chunks per batch (phase 3)
#define NMAT 31          // chunk matrices: chunk c covers t in [16c+1, 16c+16]

typedef _Float16 half8 __attribute__((ext_vector_type(8)));
typedef _Float16 half4 __attribute__((ext_vector_type(4)));
typedef _Float16 half2t __attribute__((ext_vector_type(2)));
typedef float floatx4 __attribute__((ext_vector_type(4)));

#if defined(__has_builtin)
#if __has_builtin(__builtin_amdgcn_fdot2)
#define HAVE_FDOT2 1
#endif
#endif

static __device__ __forceinline__ float dot2f(half2t a, half2t b, float c) {
#ifdef HAVE_FDOT2
    return __builtin_amdgcn_fdot2(a, b, c, false);
#else
    return fmaf((float)a[0], (float)b[0], fmaf((float)a[1], (float)b[1], c));
#endif
}

// ---------------- ws layout (bytes) ----------------
// PST : f16 [BATCH][NMAT] chunks; chunk layout: 16B unit u = K*128 + j holds
//       P[enter=K*8+e][exit=j], e=0..7
#define WS_PST   0
#define WS_ETA   16252928
#define WS_ETB   16285696
#define WS_SLOG  16320512
#define WS_AENT  16322496
#define WS_MT    16584640
#define WS_NEED  16584644

// Frag conventions (validated R2-R8):
//  A-frag tile(mt,kt): lane(quad,lm) holds A[mt*16+lm][kt*32+quad*8 .. +8]
//  B-frag tile(kt,nt): lane(quad,lm) holds B[kt*32+quad*8 .. +8][nt*16+lm]
//  C/D  tile(mt,nt):   lane(quad,lm) reg q = C[mt*16+quad*4+q][nt*16+lm]
//  padded B layout halfs: bofs(k,n) = ((n>>4)*16 + (k>>3))*136 + (n&15)*8 + (k&7)

// ================= prep: build EtA (A-layout) + EtB (padded B-layout) ==========
__global__ __launch_bounds__(256) void crf_prep2(const float* __restrict__ trans,
                                                 _Float16* __restrict__ EtA,
                                                 _Float16* __restrict__ EtB,
                                                 float* __restrict__ mTout)
{
    const int tid = threadIdx.x;
    __shared__ float slot[4];
    __shared__ __align__(16) _Float16 sb[17408];

    float mt = -INFINITY;
    for (int s = 0; s < 64; ++s) mt = fmaxf(mt, trans[tid + s * 256]);
    #pragma unroll
    for (int o = 32; o; o >>= 1) mt = fmaxf(mt, __shfl_xor(mt, o));
    if ((tid & 63) == 0) slot[tid >> 6] = mt;
    __syncthreads();
    const float mT = fmaxf(fmaxf(slot[0], slot[1]), fmaxf(slot[2], slot[3]));

    // EtA = E^T in A-layout
    for (int s = 0; s < 64; ++s) {
        int e = tid + s * 256;
        int k = e >> 7, m = e & 127;
        float v = __expf(trans[e] - mT);
        sb[((((m >> 4) * 4 + (k >> 5)) * 4 + ((k >> 3) & 3)) * 16 + (m & 15)) * 8 + (k & 7)] =
            (_Float16)v;
    }
    __syncthreads();
    for (int s = 0; s < 8; ++s) {
        int x = (tid + s * 256) * 8;
        *(half8*)&EtA[x] = *(const half8*)&sb[x];
    }
    __syncthreads();

    // EtB: element (k=j, n=i) = E[i][j], padded B-layout
    for (int s = 0; s < 64; ++s) {
        int e = tid + s * 256;
        int i = e >> 7, j = e & 127;
        float v = __expf(trans[e] - mT);
        sb[((i >> 4) * 16 + (j >> 3)) * 136 + (i & 15) * 8 + (j & 7)] = (_Float16)v;
    }
    __syncthreads();
    for (int s = 0; s < 9; ++s) {
        int g = tid + s * 256;
        if (g < 2176) {
            int x = g * 8;
            *(half8*)&EtB[x] = *(const half8*)&sb[x];
        }
    }
    if (tid == 0) mTout[0] = mT;
}

// ================= phase 1 v4: double-buffered LDS, lag-1 norm, 1 barrier/iter =
// buf[src] -> MFMA -> scale by g, divide by PREVIOUS iter's max (slotV[src]) ->
// buf[dst]; current max -> slotV[dst]. S logs exactly what is divided out.
__global__ __launch_bounds__(256, 2) void crf_chunkmat4(
    const float* __restrict__ em,
    const _Float16* __restrict__ EtA, const _Float16* __restrict__ EtB,
    const float* __restrict__ mTws,
    _Float16* __restrict__ Pst, float* __restrict__ Sout)
{
    const int c = blockIdx.x;     // 0..NMAT-1
    const int b = blockIdx.y;
    const int tid = threadIdx.x;
    const int w = tid >> 6, lane = tid & 63;
    const int quad = lane >> 4, lm = lane & 15;

    __shared__ __align__(16) _Float16 buf[2][17408];   // 69.6 KB double buffer
    __shared__ __align__(16) float gAll[16 * KDIM];    // 8 KB
    __shared__ float mE[16];
    __shared__ float slotV[2][4];

    const float mT = mTws[0];
    const int t0 = c * CH_L + 1;
    const float* emb = em + (size_t)b * TLEN * KDIM;

    // A fragments (E^T), loop-invariant
    half8 EA[2][4];
    #pragma unroll
    for (int r = 0; r < 2; ++r) {
        const int tr = 2 * w + r;
        #pragma unroll
        for (int kt = 0; kt < 4; ++kt)
            EA[r][kt] = *(const half8*)&EtA[(((tr * 4 + kt) * 4 + quad) * 16 + lm) * 8];
    }

    // stage em rows
    #pragma unroll
    for (int s = 0; s < 2; ++s) {
        int i4 = tid + s * 256;
        *(float4*)&gAll[i4 * 4] = *(const float4*)&emb[t0 * KDIM + i4 * 4];
    }
    __syncthreads();

    // per-row maxes
    #pragma unroll
    for (int r2 = 0; r2 < 4; ++r2) {
        const int r = w * 4 + r2;
        float v = fmaxf(gAll[r * KDIM + lane], gAll[r * KDIM + 64 + lane]);
        #pragma unroll
        for (int o = 32; o; o >>= 1) v = fmaxf(v, __shfl_xor(v, o));
        if (lane == 0) mE[r] = v;
    }
    __syncthreads();

    // g in place
    #pragma unroll
    for (int s = 0; s < 8; ++s) {
        int idx = tid + s * 256;
        gAll[idx] = __expf(gAll[idx] - mE[idx >> 7]);
    }
    __syncthreads();

    // init buf[0] = diag(g0)*E^T, track its max (lmax_0) for lag-1 norm
    float lm0 = 0.f;
    for (int s = 0; s < 8; ++s) {
        int g = tid + s * 256;
        int row = g >> 4, nl = g & 15;
        int addr = row * 136 + nl * 8;
        int j0 = (row & 15) * 8;
        half8 e = *(const half8*)&EtB[addr];
        const float* g0p = &gAll[j0];
        half8 o;
        #pragma unroll
        for (int x = 0; x < 8; ++x) {
            float v = (float)e[x] * g0p[x];
            lm0 = fmaxf(lm0, v);
            o[x] = (_Float16)v;
        }
        *(half8*)&buf[0][addr] = o;
    }
    #pragma unroll
    for (int o = 32; o; o >>= 1) lm0 = fmaxf(lm0, __shfl_xor(lm0, o));
    if (lane == 0) slotV[0][w] = lm0;

    float S = mT;
    if (tid == 0) {
        #pragma unroll
        for (int r = 0; r < 16; ++r) S += mE[r];
    }
    __syncthreads();   // buf[0] + slotV[0] ready

    floatx4 acc[2][8];

    for (int it = 1; it < 16; ++it) {
        const int src = (it - 1) & 1, dst = it & 1;
        const float rr = fmaxf(fmaxf(slotV[src][0], slotV[src][1]),
                               fmaxf(slotV[src][2], slotV[src][3]));
        const float rinv = 1.0f / rr;
        if (tid == 0) S += mT + __logf(rr);

        #pragma unroll
        for (int r = 0; r < 2; ++r)
            #pragma unroll
            for (int nt = 0; nt < 8; ++nt)
                acc[r][nt] = (floatx4){0.f, 0.f, 0.f, 0.f};

        const _Float16* bsrc = &buf[src][0];
        #pragma unroll
        for (int kt = 0; kt < 4; ++kt) {
            #pragma unroll
            for (int nt = 0; nt < 8; ++nt) {
                half8 bb = *(const half8*)&bsrc[(nt * 16 + kt * 4 + quad) * 136 + lm * 8];
                acc[0][nt] = __builtin_amdgcn_mfma_f32_16x16x32_f16(EA[0][kt], bb, acc[0][nt], 0, 0, 0);
                acc[1][nt] = __builtin_amdgcn_mfma_f32_16x16x32_f16(EA[1][kt], bb, acc[1][nt], 0, 0, 0);
            }
        }

        const float* gc = &gAll[it * KDIM];
        const float4 gr0 = *(const float4*)&gc[(2 * w + 0) * 16 + quad * 4];
        const float4 gr1 = *(const float4*)&gc[(2 * w + 1) * 16 + quad * 4];

        float lmax = 0.f;
        #pragma unroll
        for (int nt = 0; nt < 8; ++nt) {
            floatx4 v0 = acc[0][nt], v1 = acc[1][nt];
            float a0 = fmaxf(fmaxf(v0.x * gr0.x, v0.y * gr0.y), fmaxf(v0.z * gr0.z, v0.w * gr0.w));
            float a1 = fmaxf(fmaxf(v1.x * gr1.x, v1.y * gr1.y), fmaxf(v1.z * gr1.z, v1.w * gr1.w));
            lmax = fmaxf(lmax, fmaxf(a0, a1));
        }
        #pragma unroll
        for (int o = 32; o; o >>= 1) lmax = fmaxf(lmax, __shfl_xor(lmax, o));
        if (lane == 0) slotV[dst][w] = lmax;

        // writeback buf[dst] = diag(g)*C / rr_prev
        const float4 s0 = {gr0.x * rinv, gr0.y * rinv, gr0.z * rinv, gr0.w * rinv};
        const float4 s1 = {gr1.x * rinv, gr1.y * rinv, gr1.z * rinv, gr1.w * rinv};
        const int jlb = (quad & 1) * 4;
        _Float16* bdst = &buf[dst][0];
        #pragma unroll
        for (int r = 0; r < 2; ++r) {
            const int tr = 2 * w + r;
            const int kh = tr * 2 + (quad >> 1);
            const float4 sc = r ? s1 : s0;
            #pragma unroll
            for (int nt = 0; nt < 8; ++nt) {
                const floatx4 v = acc[r][nt];
                half4 o;
                o[0] = (_Float16)(v.x * sc.x);
                o[1] = (_Float16)(v.y * sc.y);
                o[2] = (_Float16)(v.z * sc.z);
                o[3] = (_Float16)(v.w * sc.w);
                *(half4*)&bdst[(nt * 16 + kh) * 136 + lm * 8 + jlb] = o;
            }
        }
        __syncthreads();                 // single barrier per iteration
    }

    // final matrix is buf[1] (it=15 -> dst=1); store in scan layout
    _Float16* Pc = Pst + ((size_t)(b * NMAT + c)) * 16384;
    for (int s = 0; s < 8; ++s) {
        int u = tid + s * 256;
        int K = u >> 7, j = u & 127;
        const int base = ((K >> 1) * 16 + (j >> 3)) * 136 + (j & 7);
        const int eoff = (K & 1) * 64;
        half8 v;
        #pragma unroll
        for (int e = 0; e < 8; ++e) v[e] = buf[1][base + eoff + e * 8];
        *(half8*)&Pc[u * 8] = v;
    }
    if (tid == 0) Sout[b * NMAT + c] = S;
}

// ================= phase 2: scanw — one wave per batch (R8, proven) ============
__global__ __launch_bounds__(64, 1) void crf_scanw(
    const float* __restrict__ em, const _Float16* __restrict__ Pst,
    const float* __restrict__ S, float* __restrict__ aEnter)
{
    const int b = blockIdx.x;
    const int lane = threadIdx.x;
    const int j0 = 2 * lane;

    __shared__ __align__(16) _Float16 pbuf[KDIM];
    __shared__ float Sl[NMAT];

    const _Float16* Pb = Pst + (size_t)b * NMAT * 16384;
    float* aeb = aEnter + (size_t)b * NCH * KDIM;

    if (lane < NMAT) Sl[lane] = S[b * NMAT + lane];

    float2 a0 = *(const float2*)&em[(size_t)b * TLEN * KDIM + j0];
    float mx = fmaxf(a0.x, a0.y);
    #pragma unroll
    for (int o = 32; o; o >>= 1) mx = fmaxf(mx, __shfl_xor(mx, o));
    float L = mx;
    *(float2*)&aeb[j0] = a0;
    {
        half2t p2;
        p2[0] = (_Float16)__expf(a0.x - L);
        p2[1] = (_Float16)__expf(a0.y - L);
        ((half2t*)pbuf)[lane] = p2;
    }

    half8 PA[2][16], PB[2][16];
    {
        const _Float16* Pc = Pb;
        #pragma unroll
        for (int K = 0; K < 16; ++K) {
            PA[0][K] = *(const half8*)&Pc[(K * 128 + j0) * 8];
            PA[1][K] = *(const half8*)&Pc[(K * 128 + j0) * 8 + 8];
        }
    }

    auto step = [&](const half8 (&P)[2][16], int c) {
        float q0 = 0.f, q1 = 0.f;
        #pragma unroll
        for (int K = 0; K < 16; ++K) {
            const float4 w = *(const float4*)&pbuf[K * 8];
            const half2t pw0 = __builtin_bit_cast(half2t, w.x);
            const half2t pw1 = __builtin_bit_cast(half2t, w.y);
            const half2t pw2 = __builtin_bit_cast(half2t, w.z);
            const half2t pw3 = __builtin_bit_cast(half2t, w.w);
            const half2t* c0 = (const half2t*)&P[0][K];
            const half2t* c1 = (const half2t*)&P[1][K];
            q0 = dot2f(pw0, c0[0], q0); q0 = dot2f(pw1, c0[1], q0);
            q0 = dot2f(pw2, c0[2], q0); q0 = dot2f(pw3, c0[3], q0);
            q1 = dot2f(pw0, c1[0], q1); q1 = dot2f(pw1, c1[1], q1);
            q1 = dot2f(pw2, c1[2], q1); q1 = dot2f(pw3, c1[3], q1);
        }
        const float s_c = Sl[c];
        const float sigma = __shfl(q0, 0);
        const float base = L + s_c;
        float2 st;
        st.x = base + __logf(q0);
        st.y = base + __logf(q1);
        *(float2*)&aeb[(c + 1) * KDIM + j0] = st;
        const float ri = 1.0f / sigma;
        half2t p2;
        p2[0] = (_Float16)(q0 * ri);
        p2[1] = (_Float16)(q1 * ri);
        ((half2t*)pbuf)[lane] = p2;
        L = base + __logf(sigma);
    };

    for (int c = 0; c < NMAT; c += 2) {
        if (c + 1 < NMAT) {
            const _Float16* Pc = Pb + (size_t)(c + 1) * 16384;
            #pragma unroll
            for (int K = 0; K < 16; ++K) {
                PB[0][K] = *(const half8*)&Pc[(K * 128 + j0) * 8];
                PB[1][K] = *(const half8*)&Pc[(K * 128 + j0) * 8 + 8];
            }
        }
        step(PA, c);
        if (c + 1 < NMAT) {
            if (c + 2 < NMAT) {
                const _Float16* Pc = Pb + (size_t)(c + 2) * 16384;
                #pragma unroll
                for (int K = 0; K < 16; ++K) {
                    PA[0][K] = *(const half8*)&Pc[(K * 128 + j0) * 8];
                    PA[1][K] = *(const half8*)&Pc[(K * 128 + j0) * 8 + 8];
                }
            }
            step(PB, c + 1);
        }
    }
}

// ================= phase 3 v4: zero in-loop VMEM replay ========================
// E=exp(trans) staged once to LDS (16B units, conflict-free b128 reads);
// all em values preloaded to regs; outputs accumulated in regs, stored after.
__global__ __launch_bounds__(256, 2) void crf_replay4(
    const float* __restrict__ trans, const float* __restrict__ em,
    const int* __restrict__ seq_lens, const float* __restrict__ aEnter,
    float* __restrict__ alpha, float* __restrict__ logZ)
{
    const int c = blockIdx.x, b = blockIdx.y;
    const int tid = threadIdx.x;
    const int j = tid & 127, h = tid >> 7;

    __shared__ __align__(16) _Float16 Elds[16384];   // 32 KB, 16B-unit layout
    __shared__ __align__(16) float p_lds[2][KDIM];
    __shared__ float part[2][KDIM];
    __shared__ float mslot[2][2];
    __shared__ float red[2];

    // stage E: unit u = K*128 + jc holds E[K*8+e][jc]
    for (int s = 0; s < 8; ++s) {
        int u = tid + s * 256;
        int K = u >> 7, jc = u & 127;
        half8 v;
        #pragma unroll
        for (int e = 0; e < 8; ++e) v[e] = (_Float16)__expf(trans[(K * 8 + e) * KDIM + jc]);
        *(half8*)&Elds[u * 8] = v;
    }

    const int len = seq_lens[b];
    const float* emb = em + (size_t)b * TLEN * KDIM;
    float* outb = alpha + (size_t)b * TLEN * KDIM;

    const int t_begin = c * CH_L + 1;
    const int t_end = (c == NCH - 1) ? (TLEN - 1) : (c * CH_L + CH_L);

    // preload em for all steps of this chunk (h==0 half only uses them)
    float em_r[16];
    if (h == 0) {
        #pragma unroll
        for (int i = 0; i < 16; ++i)
            em_r[i] = (t_begin + i <= t_end) ? emb[(t_begin + i) * KDIM + j] : 0.f;
    }

    float a = 0.f, last_a = 0.f;
    float areg[16];
    if (h == 0) a = aEnter[((size_t)b * NCH + c) * KDIM + j];
    if (c == 0 && h == 0) {
        outb[j] = a;
        if (len == 1) last_a = a;
    }
    {
        float v = (h == 0) ? a : -INFINITY;
        #pragma unroll
        for (int o = 32; o; o >>= 1) v = fmaxf(v, __shfl_xor(v, o));
        if ((tid & 63) == 0 && h == 0) mslot[0][tid >> 6] = v;
    }
    __syncthreads();    // Elds + mslot ready
    float m = fmaxf(mslot[0][0], mslot[0][1]);

    #pragma unroll
    for (int i = 0; i < 16; ++i) {
        const int t = t_begin + i;
        if (t > t_end) break;              // uniform across block
        const int par = i & 1;
        if (h == 0) {
            p_lds[par][j] = __expf(a - m);
            float v = a;
            #pragma unroll
            for (int o = 32; o; o >>= 1) v = fmaxf(v, __shfl_xor(v, o));
            if ((tid & 63) == 0) mslot[par][tid >> 6] = v;
        }
        __syncthreads();                   // lgkm only
        float acc0 = 0.f, acc1 = 0.f;
        #pragma unroll
        for (int s = 0; s < 8; ++s) {
            const int K = h * 8 + s;
            const half8 E8 = *(const half8*)&Elds[(K * 128 + j) * 8];
            const float4 pa = *(const float4*)&p_lds[par][K * 8];
            const float4 pb = *(const float4*)&p_lds[par][K * 8 + 4];
            acc0 = fmaf(pa.x, (float)E8[0], acc0);
            acc0 = fmaf(pa.y, (float)E8[1], acc0);
            acc0 = fmaf(pa.z, (float)E8[2], acc0);
            acc0 = fmaf(pa.w, (float)E8[3], acc0);
            acc1 = fmaf(pb.x, (float)E8[4], acc1);
            acc1 = fmaf(pb.y, (float)E8[5], acc1);
            acc1 = fmaf(pb.z, (float)E8[6], acc1);
            acc1 = fmaf(pb.w, (float)E8[7], acc1);
        }
        if (h) part[par][j] = acc0 + acc1;
        __syncthreads();                   // lgkm only
        if (h == 0) {
            const float q = (acc0 + acc1) + part[par][j];
            a = em_r[i] + m + __logf(q);
            areg[i] = a;
            if (t == len - 1) last_a = a;
            m = fmaxf(mslot[par][0], mslot[par][1]);
        }
    }

    // write all outputs (coalesced, off the serial path)
    if (h == 0) {
        #pragma unroll
        for (int i = 0; i < 16; ++i) {
            const int t = t_begin + i;
            if (t <= t_end) outb[t * KDIM + j] = areg[i];
        }
    }

    const bool blockowns = (len == 1) ? (c == 0) : (((len - 2) >> 4) == c);
    __syncthreads();
    if (blockowns) {
        float v = (h == 0) ? last_a : -INFINITY;
        #pragma unroll
        for (int o = 32; o; o >>= 1) v = fmaxf(v, __shfl_xor(v, o));
        if ((tid & 63) == 0 && h == 0) mslot[0][tid >> 6] = v;
        __syncthreads();
        const float m2 = fmaxf(mslot[0][0], mslot[0][1]);
        float e = (h == 0) ? __expf(last_a - m2) : 0.f;
        #pragma unroll
        for (int o = 32; o; o >>= 1) e += __shfl_xor(e, o);
        if ((tid & 63) == 0 && h == 0) red[tid >> 6] = e;
        __syncthreads();
        if (tid == 0) logZ[b] = m2 + __logf(red[0] + red[1]);
    }
}

// ================= fallback (proven R1 kernel) for small ws =================
__global__ __launch_bounds__(256) void crf_forward_fallback(
    const float* __restrict__ trans, const float* __restrict__ em,
    const int* __restrict__ seq_lens, float* __restrict__ alpha_out,
    float* __restrict__ logZ_out)
{
    const int b = blockIdx.x;
    const int tid = threadIdx.x;
    const int j = tid & (KDIM - 1);
    const int h = tid >> 7;

    __shared__ __align__(16) float p_lds[KDIM];
    __shared__ float part[KDIM];
    __shared__ float red[8];

    float Ereg[64];
    #pragma unroll
    for (int k = 0; k < 64; ++k) Ereg[k] = __expf(trans[(h * 64 + k) * KDIM + j]);

    const int len = seq_lens[b];
    const float* emb = em + (size_t)b * TLEN * KDIM;
    float* outb = alpha_out + (size_t)b * TLEN * KDIM;

    float a = 0.f, last_a = 0.f;
    if (h == 0) {
        a = emb[j];
        outb[j] = a;
        if (len == 1) last_a = a;
    }
    for (int t = 1; t < TLEN; ++t) {
        {
            float v = (h == 0) ? a : -INFINITY;
            #pragma unroll
            for (int o = 32; o >= 1; o >>= 1) v = fmaxf(v, __shfl_xor(v, o));
            if ((tid & 63) == 0) red[tid >> 6] = v;
        }
        __syncthreads();
        const float m = fmaxf(red[0], red[1]);
        if (h == 0) p_lds[j] = __expf(a - m);
        __syncthreads();
        float em_t = 0.f;
        if (h == 0) em_t = emb[t * KDIM + j];
        float acc0 = 0.f, acc1 = 0.f, acc2 = 0.f, acc3 = 0.f;
        const float4* p4 = (const float4*)(p_lds + h * 64);
        #pragma unroll
        for (int k4 = 0; k4 < 16; ++k4) {
            float4 pv = p4[k4];
            acc0 = fmaf(pv.x, Ereg[4 * k4 + 0], acc0);
            acc1 = fmaf(pv.y, Ereg[4 * k4 + 1], acc1);
            acc2 = fmaf(pv.z, Ereg[4 * k4 + 2], acc2);
            acc3 = fmaf(pv.w, Ereg[4 * k4 + 3], acc3);
        }
        const float acc = (acc0 + acc1) + (acc2 + acc3);
        if (h == 1) part[j] = acc;
        __syncthreads();
        if (h == 0) {
            const float q = acc + part[j];
            a = em_t + m + __logf(q);
            outb[t * KDIM + j] = a;
            if (t == len - 1) last_a = a;
        }
    }
    {
        float v = (h == 0) ? last_a : -INFINITY;
        #pragma unroll
        for (int o = 32; o >= 1; o >>= 1) v = fmaxf(v, __shfl_xor(v, o));
        if ((tid & 63) == 0) red[tid >> 6] = v;
    }
    __syncthreads();
    const float m2 = fmaxf(red[0], red[1]);
    float e = (h == 0) ? __expf(last_a - m2) : 0.f;
    #pragma unroll
    for (int o = 32; o >= 1; o >>= 1) e += __shfl_xor(e, o);
    if ((tid & 63) == 0) red[4 + (tid >> 6)] = e;
    __syncthreads();
    if (tid == 0) logZ_out[b] = m2 + logf(red[4] + red[5]);
}

extern "C" void kernel_launch(void* const* d_in, const int* in_sizes, int n_in,
                              void* d_out, int out_size, void* d_ws, size_t ws_size,
                              hipStream_t stream) {
    const float* trans    = (const float*)d_in[0];   // K*K
    const float* em       = (const float*)d_in[1];   // B*T*K
    const int*   seq_lens = (const int*)d_in[2];     // B

    float* alpha_out = (float*)d_out;                            // B*T*K
    float* logZ_out  = alpha_out + (size_t)BATCH * TLEN * KDIM;  // B

    if (ws_size < (size_t)WS_NEED) {
        crf_forward_fallback<<<BATCH, 256, 0, stream>>>(trans, em, seq_lens,
                                                        alpha_out, logZ_out);
        return;
    }

    char* ws = (char*)d_ws;
    _Float16* Pst  = (_Float16*)(ws + WS_PST);
    _Float16* EtA  = (_Float16*)(ws + WS_ETA);
    _Float16* EtB  = (_Float16*)(ws + WS_ETB);
    float*    Slog = (float*)(ws + WS_SLOG);
    float*    aEnt = (float*)(ws + WS_AENT);
    float*    mTws = (float*)(ws + WS_MT);

    crf_prep2<<<1, 256, 0, stream>>>(trans, EtA, EtB, mTws);
    crf_chunkmat4<<<dim3(NMAT, BATCH), 256, 0, stream>>>(em, EtA, EtB, mTws, Pst, Slog);
    crf_scanw<<<BATCH, 64, 0, stream>>>(em, Pst, Slog, aEnt);
    crf_replay4<<<dim3(NCH, BATCH), 256, 0, stream>>>(trans, em, seq_lens, aEnt,
                                                      alpha_out, logZ_out);
}

// Round 10
// 175.195 us; speedup vs baseline: 1.0334x; 1.0334x over previous
//
#include <hip/hip_runtime.h>
#include <math.h>

#define KDIM 128
#define TLEN 512
#define BATCH 16
#define CH_L 16
#define NCH 32           // chunks per batch (phase 3)
#define NMAT 31          // chunk matrices: chunk c covers t in [16c+1, 16c+16]

typedef _Float16 half8 __attribute__((ext_vector_type(8)));
typedef _Float16 half4 __attribute__((ext_vector_type(4)));
typedef _Float16 half2t __attribute__((ext_vector_type(2)));
typedef float floatx4 __attribute__((ext_vector_type(4)));

#if defined(__has_builtin)
#if __has_builtin(__builtin_amdgcn_fdot2)
#define HAVE_FDOT2 1
#endif
#endif

static __device__ __forceinline__ float dot2f(half2t a, half2t b, float c) {
#ifdef HAVE_FDOT2
    return __builtin_amdgcn_fdot2(a, b, c, false);
#else
    return fmaf((float)a[0], (float)b[0], fmaf((float)a[1], (float)b[1], c));
#endif
}

// ---------------- ws layout (bytes) ----------------
// PST : f16 [BATCH][NMAT] chunks; chunk layout: 16B unit u = K*128 + j holds
//       P[enter=K*8+e][exit=j], e=0..7
#define WS_PST   0
#define WS_ETA   16252928
#define WS_ETB   16285696
#define WS_SLOG  16320512
#define WS_AENT  16322496
#define WS_MT    16584640
#define WS_NEED  16584644

// Frag conventions (validated R2-R9):
//  A-frag tile(mt,kt): lane(quad,lm) holds A[mt*16+lm][kt*32+quad*8 .. +8]
//  B-frag tile(kt,nt): lane(quad,lm) holds B[kt*32+quad*8 .. +8][nt*16+lm]
//  C/D  tile(mt,nt):   lane(quad,lm) reg q = C[mt*16+quad*4+q][nt*16+lm]
//  padded B layout halfs: bofs(k,n) = ((n>>4)*16 + (k>>3))*136 + (n&15)*8 + (k&7)

// ================= prep: build EtA (A-layout) + EtB (padded B-layout) ==========
__global__ __launch_bounds__(256) void crf_prep2(const float* __restrict__ trans,
                                                 _Float16* __restrict__ EtA,
                                                 _Float16* __restrict__ EtB,
                                                 float* __restrict__ mTout)
{
    const int tid = threadIdx.x;
    __shared__ float slot[4];
    __shared__ __align__(16) _Float16 sb[17408];

    float mt = -INFINITY;
    for (int s = 0; s < 64; ++s) mt = fmaxf(mt, trans[tid + s * 256]);
    #pragma unroll
    for (int o = 32; o; o >>= 1) mt = fmaxf(mt, __shfl_xor(mt, o));
    if ((tid & 63) == 0) slot[tid >> 6] = mt;
    __syncthreads();
    const float mT = fmaxf(fmaxf(slot[0], slot[1]), fmaxf(slot[2], slot[3]));

    // EtA = E^T in A-layout
    for (int s = 0; s < 64; ++s) {
        int e = tid + s * 256;
        int k = e >> 7, m = e & 127;
        float v = __expf(trans[e] - mT);
        sb[((((m >> 4) * 4 + (k >> 5)) * 4 + ((k >> 3) & 3)) * 16 + (m & 15)) * 8 + (k & 7)] =
            (_Float16)v;
    }
    __syncthreads();
    for (int s = 0; s < 8; ++s) {
        int x = (tid + s * 256) * 8;
        *(half8*)&EtA[x] = *(const half8*)&sb[x];
    }
    __syncthreads();

    // EtB: element (k=j, n=i) = E[i][j], padded B-layout
    for (int s = 0; s < 64; ++s) {
        int e = tid + s * 256;
        int i = e >> 7, j = e & 127;
        float v = __expf(trans[e] - mT);
        sb[((i >> 4) * 16 + (j >> 3)) * 136 + (i & 15) * 8 + (j & 7)] = (_Float16)v;
    }
    __syncthreads();
    for (int s = 0; s < 9; ++s) {
        int g = tid + s * 256;
        if (g < 2176) {
            int x = g * 8;
            *(half8*)&EtB[x] = *(const half8*)&sb[x];
        }
    }
    if (tid == 0) mTout[0] = mT;
}

// ================= phase 1: chunk products, zero in-loop VMEM (R6, proven) =====
__global__ __launch_bounds__(256, 2) void crf_chunkmat3(
    const float* __restrict__ em,
    const _Float16* __restrict__ EtA, const _Float16* __restrict__ EtB,
    const float* __restrict__ mTws,
    _Float16* __restrict__ Pst, float* __restrict__ Sout)
{
    const int c = blockIdx.x;     // 0..NMAT-1
    const int b = blockIdx.y;
    const int tid = threadIdx.x;
    const int w = tid >> 6, lane = tid & 63;
    const int quad = lane >> 4, lm = lane & 15;

    __shared__ __align__(16) _Float16 buf[17408];   // 34.8 KB padded B-layout
    __shared__ __align__(16) float gAll[16 * KDIM]; // 8 KB
    __shared__ float mE[16];
    __shared__ float slotV[4];

    const float mT = mTws[0];
    const int t0 = c * CH_L + 1;
    const float* emb = em + (size_t)b * TLEN * KDIM;

    half8 EA[2][4];
    #pragma unroll
    for (int r = 0; r < 2; ++r) {
        const int tr = 2 * w + r;
        #pragma unroll
        for (int kt = 0; kt < 4; ++kt)
            EA[r][kt] = *(const half8*)&EtA[(((tr * 4 + kt) * 4 + quad) * 16 + lm) * 8];
    }

    #pragma unroll
    for (int s = 0; s < 2; ++s) {
        int i4 = tid + s * 256;
        *(float4*)&gAll[i4 * 4] = *(const float4*)&emb[t0 * KDIM + i4 * 4];
    }
    __syncthreads();

    #pragma unroll
    for (int r2 = 0; r2 < 4; ++r2) {
        const int r = w * 4 + r2;
        float v = fmaxf(gAll[r * KDIM + lane], gAll[r * KDIM + 64 + lane]);
        #pragma unroll
        for (int o = 32; o; o >>= 1) v = fmaxf(v, __shfl_xor(v, o));
        if (lane == 0) mE[r] = v;
    }
    __syncthreads();

    #pragma unroll
    for (int s = 0; s < 8; ++s) {
        int idx = tid + s * 256;
        gAll[idx] = __expf(gAll[idx] - mE[idx >> 7]);
    }
    __syncthreads();

    for (int s = 0; s < 8; ++s) {
        int g = tid + s * 256;
        int row = g >> 4, nl = g & 15;
        int addr = row * 136 + nl * 8;
        int j0 = (row & 15) * 8;
        half8 e = *(const half8*)&EtB[addr];
        const float* g0p = &gAll[j0];
        half8 o;
        #pragma unroll
        for (int x = 0; x < 8; ++x) o[x] = (_Float16)((float)e[x] * g0p[x]);
        *(half8*)&buf[addr] = o;
    }
    float S = mT;
    if (tid == 0) {
        #pragma unroll
        for (int r = 0; r < 16; ++r) S += mE[r];
    }
    __syncthreads();

    floatx4 acc[2][8];

    for (int it = 1; it < 16; ++it) {
        #pragma unroll
        for (int r = 0; r < 2; ++r)
            #pragma unroll
            for (int nt = 0; nt < 8; ++nt)
                acc[r][nt] = (floatx4){0.f, 0.f, 0.f, 0.f};

        #pragma unroll
        for (int kt = 0; kt < 4; ++kt) {
            #pragma unroll
            for (int nt = 0; nt < 8; ++nt) {
                half8 bb = *(const half8*)&buf[(nt * 16 + kt * 4 + quad) * 136 + lm * 8];
                acc[0][nt] = __builtin_amdgcn_mfma_f32_16x16x32_f16(EA[0][kt], bb, acc[0][nt], 0, 0, 0);
                acc[1][nt] = __builtin_amdgcn_mfma_f32_16x16x32_f16(EA[1][kt], bb, acc[1][nt], 0, 0, 0);
            }
        }

        const float* gc = &gAll[it * KDIM];
        const float4 gr0 = *(const float4*)&gc[(2 * w + 0) * 16 + quad * 4];
        const float4 gr1 = *(const float4*)&gc[(2 * w + 1) * 16 + quad * 4];

        float lmax = 0.f;
        #pragma unroll
        for (int nt = 0; nt < 8; ++nt) {
            floatx4 v0 = acc[0][nt], v1 = acc[1][nt];
            float a0 = fmaxf(fmaxf(v0.x * gr0.x, v0.y * gr0.y), fmaxf(v0.z * gr0.z, v0.w * gr0.w));
            float a1 = fmaxf(fmaxf(v1.x * gr1.x, v1.y * gr1.y), fmaxf(v1.z * gr1.z, v1.w * gr1.w));
            lmax = fmaxf(lmax, fmaxf(a0, a1));
        }
        #pragma unroll
        for (int o = 32; o; o >>= 1) lmax = fmaxf(lmax, __shfl_xor(lmax, o));
        if (lane == 0) slotV[w] = lmax;
        __syncthreads();                                   // barrier 1

        const float rr = fmaxf(fmaxf(slotV[0], slotV[1]), fmaxf(slotV[2], slotV[3]));
        const float rinv = 1.0f / rr;
        if (tid == 0) S += mT + __logf(rr);

        const float4 s0 = {gr0.x * rinv, gr0.y * rinv, gr0.z * rinv, gr0.w * rinv};
        const float4 s1 = {gr1.x * rinv, gr1.y * rinv, gr1.z * rinv, gr1.w * rinv};
        const int jlb = (quad & 1) * 4;
        #pragma unroll
        for (int r = 0; r < 2; ++r) {
            const int tr = 2 * w + r;
            const int kh = tr * 2 + (quad >> 1);
            const float4 sc = r ? s1 : s0;
            #pragma unroll
            for (int nt = 0; nt < 8; ++nt) {
                const floatx4 v = acc[r][nt];
                half4 o;
                o[0] = (_Float16)(v.x * sc.x);
                o[1] = (_Float16)(v.y * sc.y);
                o[2] = (_Float16)(v.z * sc.z);
                o[3] = (_Float16)(v.w * sc.w);
                *(half4*)&buf[(nt * 16 + kh) * 136 + lm * 8 + jlb] = o;
            }
        }
        __syncthreads();                                   // barrier 2
    }

    _Float16* Pc = Pst + ((size_t)(b * NMAT + c)) * 16384;
    for (int s = 0; s < 8; ++s) {
        int u = tid + s * 256;
        int K = u >> 7, j = u & 127;
        const int base = ((K >> 1) * 16 + (j >> 3)) * 136 + (j & 7);
        const int eoff = (K & 1) * 64;
        half8 v;
        #pragma unroll
        for (int e = 0; e < 8; ++e) v[e] = buf[base + eoff + e * 8];
        *(half8*)&Pc[u * 8] = v;
    }
    if (tid == 0) Sout[b * NMAT + c] = S;
}

// ================= phase 2: scanw — one wave per batch, barrier-free (R8) ======
__global__ __launch_bounds__(64, 1) void crf_scanw(
    const float* __restrict__ em, const _Float16* __restrict__ Pst,
    const float* __restrict__ S, float* __restrict__ aEnter)
{
    const int b = blockIdx.x;
    const int lane = threadIdx.x;
    const int j0 = 2 * lane;

    __shared__ __align__(16) _Float16 pbuf[KDIM];
    __shared__ float Sl[NMAT];

    const _Float16* Pb = Pst + (size_t)b * NMAT * 16384;
    float* aeb = aEnter + (size_t)b * NCH * KDIM;

    if (lane < NMAT) Sl[lane] = S[b * NMAT + lane];

    float2 a0 = *(const float2*)&em[(size_t)b * TLEN * KDIM + j0];
    float mx = fmaxf(a0.x, a0.y);
    #pragma unroll
    for (int o = 32; o; o >>= 1) mx = fmaxf(mx, __shfl_xor(mx, o));
    float L = mx;
    *(float2*)&aeb[j0] = a0;
    {
        half2t p2;
        p2[0] = (_Float16)__expf(a0.x - L);
        p2[1] = (_Float16)__expf(a0.y - L);
        ((half2t*)pbuf)[lane] = p2;
    }

    half8 PA[2][16], PB[2][16];
    {
        const _Float16* Pc = Pb;
        #pragma unroll
        for (int K = 0; K < 16; ++K) {
            PA[0][K] = *(const half8*)&Pc[(K * 128 + j0) * 8];
            PA[1][K] = *(const half8*)&Pc[(K * 128 + j0) * 8 + 8];
        }
    }

    auto step = [&](const half8 (&P)[2][16], int c) {
        float q0 = 0.f, q1 = 0.f;
        #pragma unroll
        for (int K = 0; K < 16; ++K) {
            const float4 w = *(const float4*)&pbuf[K * 8];
            const half2t pw0 = __builtin_bit_cast(half2t, w.x);
            const half2t pw1 = __builtin_bit_cast(half2t, w.y);
            const half2t pw2 = __builtin_bit_cast(half2t, w.z);
            const half2t pw3 = __builtin_bit_cast(half2t, w.w);
            const half2t* c0 = (const half2t*)&P[0][K];
            const half2t* c1 = (const half2t*)&P[1][K];
            q0 = dot2f(pw0, c0[0], q0); q0 = dot2f(pw1, c0[1], q0);
            q0 = dot2f(pw2, c0[2], q0); q0 = dot2f(pw3, c0[3], q0);
            q1 = dot2f(pw0, c1[0], q1); q1 = dot2f(pw1, c1[1], q1);
            q1 = dot2f(pw2, c1[2], q1); q1 = dot2f(pw3, c1[3], q1);
        }
        const float s_c = Sl[c];
        const float sigma = __shfl(q0, 0);
        const float base = L + s_c;
        float2 st;
        st.x = base + __logf(q0);
        st.y = base + __logf(q1);
        *(float2*)&aeb[(c + 1) * KDIM + j0] = st;
        const float ri = 1.0f / sigma;
        half2t p2;
        p2[0] = (_Float16)(q0 * ri);
        p2[1] = (_Float16)(q1 * ri);
        ((half2t*)pbuf)[lane] = p2;
        L = base + __logf(sigma);
    };

    for (int c = 0; c < NMAT; c += 2) {
        if (c + 1 < NMAT) {
            const _Float16* Pc = Pb + (size_t)(c + 1) * 16384;
            #pragma unroll
            for (int K = 0; K < 16; ++K) {
                PB[0][K] = *(const half8*)&Pc[(K * 128 + j0) * 8];
                PB[1][K] = *(const half8*)&Pc[(K * 128 + j0) * 8 + 8];
            }
        }
        step(PA, c);
        if (c + 1 < NMAT) {
            if (c + 2 < NMAT) {
                const _Float16* Pc = Pb + (size_t)(c + 2) * 16384;
                #pragma unroll
                for (int K = 0; K < 16; ++K) {
                    PA[0][K] = *(const half8*)&Pc[(K * 128 + j0) * 8];
                    PA[1][K] = *(const half8*)&Pc[(K * 128 + j0) * 8 + 8];
                }
            }
            step(PB, c + 1);
        }
    }
}

// ================= phase 3 v5: replayw — one wave per (chunk,batch), barrier-free
// Lane l owns exit columns j=l and j=l+64. E=exp(trans) columns in 128 VGPRs
// (Ea/Eb: half2 over k-pairs). p packed f16 in LDS (wave-sync, lgkm only).
// Lag normalization: sigma = q0 (col 0), p' = (q/sigma)*exp(em), L += log sigma.
// Invariant: alpha_t[j] = L + log p[j].
__global__ __launch_bounds__(64, 1) void crf_replayw(
    const float* __restrict__ trans, const float* __restrict__ em,
    const int* __restrict__ seq_lens, const float* __restrict__ aEnter,
    float* __restrict__ alpha, float* __restrict__ logZ)
{
    const int c = blockIdx.x, b = blockIdx.y;
    const int l = threadIdx.x;

    __shared__ __align__(16) _Float16 pbuf[KDIM];

    // ---- stage E columns l and l+64: Ea[t]=(E[2t][l],E[2t+1][l]) etc. ----
    half2t Ea[64], Eb[64];
    #pragma unroll
    for (int t2 = 0; t2 < 64; ++t2) {
        const float* r0 = &trans[(2 * t2) * KDIM];
        const float* r1 = &trans[(2 * t2 + 1) * KDIM];
        half2t ea, eb;
        ea[0] = (_Float16)__expf(r0[l]);
        ea[1] = (_Float16)__expf(r1[l]);
        eb[0] = (_Float16)__expf(r0[l + 64]);
        eb[1] = (_Float16)__expf(r1[l + 64]);
        Ea[t2] = ea;
        Eb[t2] = eb;
    }

    const int len = seq_lens[b];
    const float* emb = em + (size_t)b * TLEN * KDIM;
    float* outb = alpha + (size_t)b * TLEN * KDIM;
    const float* ae = aEnter + ((size_t)b * NCH + c) * KDIM;

    // ---- init from entering alpha ----
    float a0 = ae[l], a1 = ae[l + 64];
    float mx = fmaxf(a0, a1);
    #pragma unroll
    for (int o = 32; o; o >>= 1) mx = fmaxf(mx, __shfl_xor(mx, o));
    float L = mx;
    pbuf[l]      = (_Float16)__expf(a0 - L);
    pbuf[l + 64] = (_Float16)__expf(a1 - L);

    float la0 = 0.f, la1 = -INFINITY;
    if (c == 0) {
        outb[l] = a0;
        outb[l + 64] = a1;
        if (len == 1) { la0 = a0; la1 = a1; }
    }

    const int t_begin = c * CH_L + 1;
    const int t_end = (c == NCH - 1) ? (TLEN - 1) : (c * CH_L + CH_L);

    float e0 = emb[t_begin * KDIM + l];
    float e1 = emb[t_begin * KDIM + l + 64];

    for (int t = t_begin; t <= t_end; ++t) {
        // prefetch next em (off critical path)
        float n0 = 0.f, n1 = 0.f;
        if (t < t_end) {
            n0 = emb[(t + 1) * KDIM + l];
            n1 = emb[(t + 1) * KDIM + l + 64];
        }

        float q0 = 0.f, q1 = 0.f;
        #pragma unroll
        for (int s = 0; s < 16; ++s) {
            const float4 w = *(const float4*)&pbuf[s * 8];
            const half2t p0 = __builtin_bit_cast(half2t, w.x);
            const half2t p1 = __builtin_bit_cast(half2t, w.y);
            const half2t p2 = __builtin_bit_cast(half2t, w.z);
            const half2t p3 = __builtin_bit_cast(half2t, w.w);
            q0 = dot2f(p0, Ea[4 * s + 0], q0);
            q0 = dot2f(p1, Ea[4 * s + 1], q0);
            q0 = dot2f(p2, Ea[4 * s + 2], q0);
            q0 = dot2f(p3, Ea[4 * s + 3], q0);
            q1 = dot2f(p0, Eb[4 * s + 0], q1);
            q1 = dot2f(p1, Eb[4 * s + 1], q1);
            q1 = dot2f(p2, Eb[4 * s + 2], q1);
            q1 = dot2f(p3, Eb[4 * s + 3], q1);
        }

        const float A0 = e0 + L + __logf(q0);
        const float A1 = e1 + L + __logf(q1);
        outb[t * KDIM + l] = A0;
        outb[t * KDIM + l + 64] = A1;
        if (t == len - 1) { la0 = A0; la1 = A1; }

        const float sigma = __shfl(q0, 0);
        const float ri = 1.0f / sigma;
        pbuf[l]      = (_Float16)(q0 * ri * __expf(e0));
        pbuf[l + 64] = (_Float16)(q1 * ri * __expf(e1));
        L += __logf(sigma);
        e0 = n0; e1 = n1;
    }

    // ---- logZ (owning block only; pure wave ops) ----
    const bool blockowns = (len == 1) ? (c == 0) : (((len - 2) >> 4) == c);
    if (blockowns) {
        float m2 = fmaxf(la0, la1);
        #pragma unroll
        for (int o = 32; o; o >>= 1) m2 = fmaxf(m2, __shfl_xor(m2, o));
        float e = __expf(la0 - m2) + __expf(la1 - m2);
        #pragma unroll
        for (int o = 32; o; o >>= 1) e += __shfl_xor(e, o);
        if (l == 0) logZ[b] = m2 + __logf(e);
    }
}

// ================= fallback (proven R1 kernel) for small ws =================
__global__ __launch_bounds__(256) void crf_forward_fallback(
    const float* __restrict__ trans, const float* __restrict__ em,
    const int* __restrict__ seq_lens, float* __restrict__ alpha_out,
    float* __restrict__ logZ_out)
{
    const int b = blockIdx.x;
    const int tid = threadIdx.x;
    const int j = tid & (KDIM - 1);
    const int h = tid >> 7;

    __shared__ __align__(16) float p_lds[KDIM];
    __shared__ float part[KDIM];
    __shared__ float red[8];

    float Ereg[64];
    #pragma unroll
    for (int k = 0; k < 64; ++k) Ereg[k] = __expf(trans[(h * 64 + k) * KDIM + j]);

    const int len = seq_lens[b];
    const float* emb = em + (size_t)b * TLEN * KDIM;
    float* outb = alpha_out + (size_t)b * TLEN * KDIM;

    float a = 0.f, last_a = 0.f;
    if (h == 0) {
        a = emb[j];
        outb[j] = a;
        if (len == 1) last_a = a;
    }
    for (int t = 1; t < TLEN; ++t) {
        {
            float v = (h == 0) ? a : -INFINITY;
            #pragma unroll
            for (int o = 32; o >= 1; o >>= 1) v = fmaxf(v, __shfl_xor(v, o));
            if ((tid & 63) == 0) red[tid >> 6] = v;
        }
        __syncthreads();
        const float m = fmaxf(red[0], red[1]);
        if (h == 0) p_lds[j] = __expf(a - m);
        __syncthreads();
        float em_t = 0.f;
        if (h == 0) em_t = emb[t * KDIM + j];
        float acc0 = 0.f, acc1 = 0.f, acc2 = 0.f, acc3 = 0.f;
        const float4* p4 = (const float4*)(p_lds + h * 64);
        #pragma unroll
        for (int k4 = 0; k4 < 16; ++k4) {
            float4 pv = p4[k4];
            acc0 = fmaf(pv.x, Ereg[4 * k4 + 0], acc0);
            acc1 = fmaf(pv.y, Ereg[4 * k4 + 1], acc1);
            acc2 = fmaf(pv.z, Ereg[4 * k4 + 2], acc2);
            acc3 = fmaf(pv.w, Ereg[4 * k4 + 3], acc3);
        }
        const float acc = (acc0 + acc1) + (acc2 + acc3);
        if (h == 1) part[j] = acc;
        __syncthreads();
        if (h == 0) {
            const float q = acc + part[j];
            a = em_t + m + __logf(q);
            outb[t * KDIM + j] = a;
            if (t == len - 1) last_a = a;
        }
    }
    {
        float v = (h == 0) ? last_a : -INFINITY;
        #pragma unroll
        for (int o = 32; o >= 1; o >>= 1) v = fmaxf(v, __shfl_xor(v, o));
        if ((tid & 63) == 0) red[tid >> 6] = v;
    }
    __syncthreads();
    const float m2 = fmaxf(red[0], red[1]);
    float e = (h == 0) ? __expf(last_a - m2) : 0.f;
    #pragma unroll
    for (int o = 32; o >= 1; o >>= 1) e += __shfl_xor(e, o);
    if ((tid & 63) == 0) red[4 + (tid >> 6)] = e;
    __syncthreads();
    if (tid == 0) logZ_out[b] = m2 + logf(red[4] + red[5]);
}

extern "C" void kernel_launch(void* const* d_in, const int* in_sizes, int n_in,
                              void* d_out, int out_size, void* d_ws, size_t ws_size,
                              hipStream_t stream) {
    const float* trans    = (const float*)d_in[0];   // K*K
    const float* em       = (const float*)d_in[1];   // B*T*K
    const int*   seq_lens = (const int*)d_in[2];     // B

    float* alpha_out = (float*)d_out;                            // B*T*K
    float* logZ_out  = alpha_out + (size_t)BATCH * TLEN * KDIM;  // B

    if (ws_size < (size_t)WS_NEED) {
        crf_forward_fallback<<<BATCH, 256, 0, stream>>>(trans, em, seq_lens,
                                                        alpha_out, logZ_out);
        return;
    }

    char* ws = (char*)d_ws;
    _Float16* Pst  = (_Float16*)(ws + WS_PST);
    _Float16* EtA  = (_Float16*)(ws + WS_ETA);
    _Float16* EtB  = (_Float16*)(ws + WS_ETB);
    float*    Slog = (float*)(ws + WS_SLOG);
    float*    aEnt = (float*)(ws + WS_AENT);
    float*    mTws = (float*)(ws + WS_MT);

    crf_prep2<<<1, 256, 0, stream>>>(trans, EtA, EtB, mTws);
    crf_chunkmat3<<<dim3(NMAT, BATCH), 256, 0, stream>>>(em, EtA, EtB, mTws, Pst, Slog);
    crf_scanw<<<BATCH, 64, 0, stream>>>(em, Pst, Slog, aEnt);
    crf_replayw<<<dim3(NCH, BATCH), 64, 0, stream>>>(trans, em, seq_lens, aEnt,
                                                     alpha_out, logZ_out);
}